// Round 9
// baseline (243.269 us; speedup 1.0000x reference)
//
#include <hip/hip_runtime.h>
#include <hip/hip_bf16.h>

// B=2, S=2048, D=1024, H=16, DH=64. fp32 in/out; bf16 MFMA inside.
#define BB 2
#define SS 2048
#define DD 1024
#define HH 16
#define DHH 64
#define MM (BB * SS)  // 4096

typedef unsigned short u16;
using v8s   = __attribute__((ext_vector_type(8))) short;   // 8 bf16 (4 VGPRs)
using f32x4 = __attribute__((ext_vector_type(4))) float;   // MFMA C/D frag

#define LOG2E 1.44269504088896340736f

// raw v_exp_f32 if available (base-2); else __expf (base-e). Scales follow.
#if __has_builtin(__builtin_amdgcn_exp2f)
#define EXP_RAW(x) __builtin_amdgcn_exp2f(x)
#define QSCALE (0.125f * LOG2E)
#define MSCALE LOG2E
#else
#define EXP_RAW(x) __expf(x)
#define QSCALE 0.125f
#define MSCALE 1.0f
#endif

__device__ __forceinline__ u16 f2bf(float f) {
  unsigned int u = __float_as_uint(f);
  u += 0x7fffu + ((u >> 16) & 1u);
  return (u16)(u >> 16);
}

// two fp32 -> packed bf16x2 (RNE)
__device__ __forceinline__ unsigned int pk2(float a, float b) {
  __hip_bfloat162 h = __float22bfloat162_rn(float2{a, b});
  return *(unsigned int*)&h;
}

// async global->LDS, 16 B per lane; dest = wave-uniform base + lane*16
__device__ __forceinline__ void async_cp16(const u16* g, u16* l) {
  __builtin_amdgcn_global_load_lds(
      (const __attribute__((address_space(1))) unsigned int*)g,
      (__attribute__((address_space(3))) unsigned int*)l, 16, 0, 0);
}

// XOR swizzle of 16B chunk index within 8-chunk (128 B) groups, keyed by row
__device__ __forceinline__ int swz(int r, int c8) {
  return (c8 & ~7) | ((c8 ^ r) & 7);
}

// ---------------------------------------------------------------------------
// Prep: fused fp32->bf16 activation convert (blocks 0..12287) and
// W->W^T bf16 transpose (blocks 12288..13311).
// ---------------------------------------------------------------------------
__global__ __launch_bounds__(256) void prep_all(
    const float* __restrict__ x0, const float* __restrict__ x1,
    const float* __restrict__ x2,
    u16* __restrict__ y0, u16* __restrict__ y1, u16* __restrict__ y2,
    const float* __restrict__ W0, const float* __restrict__ W1,
    const float* __restrict__ W2, const float* __restrict__ W3,
    u16* __restrict__ T0, u16* __restrict__ T1,
    u16* __restrict__ T2, u16* __restrict__ T3) {
  __shared__ u16 T[64][72];
  const int bid = blockIdx.x;
  const int tid = threadIdx.x;
  if (bid < 12288) {
    const int z = bid >> 12;           // 4096 blocks per tensor
    const int bx = bid & 4095;
    const float* x = z == 0 ? x0 : (z == 1 ? x1 : x2);
    u16* y = z == 0 ? y0 : (z == 1 ? y1 : y2);
    int i = (bx * 256 + tid) * 4;
    float4 v = *(const float4*)(x + i);
    uint2 u;
    u.x = pk2(v.x, v.y);
    u.y = pk2(v.z, v.w);
    *(uint2*)(y + i) = u;
  } else {
    const int t = bid - 12288;
    const int z = t >> 8;
    const int tile = t & 255;
    const float* W = z == 0 ? W0 : (z == 1 ? W1 : (z == 2 ? W2 : W3));
    u16* Wt = z == 0 ? T0 : (z == 1 ? T1 : (z == 2 ? T2 : T3));
    const int n0 = (tile & 15) * 64, k0 = (tile >> 4) * 64;
#pragma unroll
    for (int i = 0; i < 4; i++) {
      int idx = tid + i * 256;
      int r = idx >> 4, c = (idx & 15) * 4;
      float4 x = *(const float4*)(W + (long)(k0 + r) * DD + n0 + c);
      T[c + 0][r] = f2bf(x.x);
      T[c + 1][r] = f2bf(x.y);
      T[c + 2][r] = f2bf(x.z);
      T[c + 3][r] = f2bf(x.w);
    }
    __syncthreads();
#pragma unroll
    for (int i = 0; i < 2; i++) {
      int idx = tid + i * 256;
      int n = idx >> 3, kc = (idx & 7) * 8;
      *(v8s*)(Wt + (long)(n0 + n) * DD + k0 + kc) = *(const v8s*)&T[n][kc];
    }
  }
}

// ---------------------------------------------------------------------------
// Fused Q/K/V projection GEMM: 128x128 tile, BK=64, global_load_lds.
// z = 0(q)/1(k)/2(v). q gets *QSCALE (folded attn scale + softmax base).
// out: q,k [B,H,S,DH]; v [B,H,DH,S]. Epilogue transposes via LDS (coalesced).
// ---------------------------------------------------------------------------
__global__ __launch_bounds__(256, 3) void proj_fused(
    const u16* __restrict__ qb, const u16* __restrict__ kb, const u16* __restrict__ vb,
    const u16* __restrict__ Wqt, const u16* __restrict__ Wkt, const u16* __restrict__ Wvt,
    const float* __restrict__ bq, const float* __restrict__ bk, const float* __restrict__ bv,
    u16* __restrict__ qo, u16* __restrict__ ko, u16* __restrict__ vo) {
  __shared__ union ShU {
    struct { u16 As[128 * 64]; u16 Bs[128 * 64]; } st;  // 32 KB
    u16 T[128 * 136];                                   // 34.8 KB
  } sh;
  const int z = blockIdx.z;
  const u16* A  = z == 0 ? qb : (z == 1 ? kb : vb);
  const u16* Bt = z == 0 ? Wqt : (z == 1 ? Wkt : Wvt);
  const float* bias = z == 0 ? bq : (z == 1 ? bk : bv);
  u16* out = z == 0 ? qo : (z == 1 ? ko : vo);
  const float scale = z == 0 ? QSCALE : 1.0f;

  const int tid = threadIdx.x;
  const int w = tid >> 6, lane = tid & 63;
  const int quad = lane >> 4, lq = lane & 15;
  const int wm = w >> 1, wn = w & 1;
  const int row0 = blockIdx.y * 128, col0 = blockIdx.x * 128;

  f32x4 acc[4][4];
#pragma unroll
  for (int i = 0; i < 4; i++)
#pragma unroll
    for (int j = 0; j < 4; j++)
#pragma unroll
      for (int r = 0; r < 4; r++) acc[i][j][r] = 0.f;

  const int cr = tid >> 3, cc = (tid & 7) * 8;  // chunk row/col (issue 0)

  for (int k0 = 0; k0 < DD; k0 += 64) {
    __syncthreads();
#pragma unroll
    for (int it = 0; it < 4; it++) {
      async_cp16(A  + (long)(row0 + cr + it * 32) * DD + k0 + cc,
                 sh.st.As + (it * 256 + w * 64) * 8);
      async_cp16(Bt + (long)(col0 + cr + it * 32) * DD + k0 + cc,
                 sh.st.Bs + (it * 256 + w * 64) * 8);
    }
    __syncthreads();

#pragma unroll
    for (int kk = 0; kk < 2; kk++) {
      v8s a[4], b[4];
#pragma unroll
      for (int i = 0; i < 4; i++)
        a[i] = *(const v8s*)&sh.st.As[(wm * 64 + i * 16 + lq) * 64 + kk * 32 + quad * 8];
#pragma unroll
      for (int j = 0; j < 4; j++)
        b[j] = *(const v8s*)&sh.st.Bs[(wn * 64 + j * 16 + lq) * 64 + kk * 32 + quad * 8];
#pragma unroll
      for (int i = 0; i < 4; i++)
#pragma unroll
        for (int j = 0; j < 4; j++)
          acc[i][j] = __builtin_amdgcn_mfma_f32_16x16x32_bf16(a[i], b[j], acc[i][j], 0, 0, 0);
    }
  }

  __syncthreads();  // staging reads done before overwriting with T

  if (z != 2) {
    // T[m][n] stride 136: scalar writes, vector reads along n
#pragma unroll
    for (int j = 0; j < 4; j++) {
      int nl = wn * 64 + j * 16 + lq;
      float bi = bias[col0 + nl];
#pragma unroll
      for (int i = 0; i < 4; i++)
#pragma unroll
        for (int r = 0; r < 4; r++) {
          int ml = wm * 64 + i * 16 + quad * 4 + r;
          sh.T[ml * 136 + nl] = f2bf((acc[i][j][r] + bi) * scale);
        }
    }
    __syncthreads();
    const int bb = row0 >> 11;
#pragma unroll
    for (int t = 0; t < 8; t++) {
      int c = tid + t * 256;            // 2048 chunks: 128 m x 16
      int m = c >> 4, jc = c & 15;
      int s = (row0 + m) & (SS - 1);
      int gn = col0 + jc * 8;
      int hh = gn >> 6, d = gn & (DHH - 1);
      long off = ((long)(bb * HH + hh) * SS + s) * DHH + d;
      *(v8s*)(out + off) = *(const v8s*)&sh.T[m * 136 + jc * 8];
    }
  } else {
    // T[n][m] stride 136: uint2 writes, vector reads along m (s-dim)
#pragma unroll
    for (int j = 0; j < 4; j++) {
      int nl = wn * 64 + j * 16 + lq;
      float bi = bias[col0 + nl];
#pragma unroll
      for (int i = 0; i < 4; i++) {
        int ml = wm * 64 + i * 16 + quad * 4;
        uint2 pk;
        pk.x = pk2(acc[i][j][0] + bi, acc[i][j][1] + bi);
        pk.y = pk2(acc[i][j][2] + bi, acc[i][j][3] + bi);
        *(uint2*)&sh.T[nl * 136 + ml] = pk;
      }
    }
    __syncthreads();
    const int bb = row0 >> 11;
#pragma unroll
    for (int t = 0; t < 8; t++) {
      int c = tid + t * 256;            // 2048 chunks: 128 n x 16
      int n = c >> 4, jc = c & 15;
      int gn = col0 + n;
      int hh = gn >> 6, d = gn & (DHH - 1);
      int s = (row0 + jc * 8) & (SS - 1);
      long off = ((long)(bb * HH + hh) * DHH + d) * SS + s;
      *(v8s*)(out + off) = *(const v8s*)&sh.T[n * 136 + jc * 8];
    }
  }
}

// ---------------------------------------------------------------------------
// Out GEMM: fp32 out = ctx(bf16)[M,K] @ Wot(bf16 [n][k]) + bo. 64x128, BK=64.
// ---------------------------------------------------------------------------
__global__ __launch_bounds__(256, 3) void out_gemm(const u16* __restrict__ A,
                                                   const u16* __restrict__ Bt,
                                                   const float* __restrict__ bias,
                                                   float* __restrict__ outp) {
  __shared__ u16 As[64 * 64];    // 8 KB
  __shared__ u16 Bs[128 * 64];   // 16 KB
  const int tid = threadIdx.x;
  const int w = tid >> 6, lane = tid & 63;
  const int quad = lane >> 4, lq = lane & 15;
  const int wm = w >> 1, wn = w & 1;
  const int row0 = blockIdx.y * 64, col0 = blockIdx.x * 128;

  f32x4 acc[2][4];
#pragma unroll
  for (int i = 0; i < 2; i++)
#pragma unroll
    for (int j = 0; j < 4; j++)
#pragma unroll
      for (int r = 0; r < 4; r++) acc[i][j][r] = 0.f;

  const int cr = tid >> 3, cc = (tid & 7) * 8;

  for (int k0 = 0; k0 < DD; k0 += 64) {
    __syncthreads();
#pragma unroll
    for (int it = 0; it < 2; it++)
      async_cp16(A + (long)(row0 + cr + it * 32) * DD + k0 + cc,
                 As + (it * 256 + w * 64) * 8);
#pragma unroll
    for (int it = 0; it < 4; it++)
      async_cp16(Bt + (long)(col0 + cr + it * 32) * DD + k0 + cc,
                 Bs + (it * 256 + w * 64) * 8);
    __syncthreads();

#pragma unroll
    for (int kk = 0; kk < 2; kk++) {
      v8s a[2], b[4];
#pragma unroll
      for (int i = 0; i < 2; i++)
        a[i] = *(const v8s*)&As[(wm * 32 + i * 16 + lq) * 64 + kk * 32 + quad * 8];
#pragma unroll
      for (int j = 0; j < 4; j++)
        b[j] = *(const v8s*)&Bs[(wn * 64 + j * 16 + lq) * 64 + kk * 32 + quad * 8];
#pragma unroll
      for (int i = 0; i < 2; i++)
#pragma unroll
        for (int j = 0; j < 4; j++)
          acc[i][j] = __builtin_amdgcn_mfma_f32_16x16x32_bf16(a[i], b[j], acc[i][j], 0, 0, 0);
    }
  }

#pragma unroll
  for (int i = 0; i < 2; i++)
#pragma unroll
    for (int j = 0; j < 4; j++) {
      int n = col0 + wn * 64 + j * 16 + lq;
      float bi = bias[n];
#pragma unroll
      for (int r = 0; r < 4; r++) {
        int m = row0 + wm * 32 + i * 16 + quad * 4 + r;
        outp[(long)m * DD + n] = acc[i][j][r] + bi;
      }
    }
}

// ---------------------------------------------------------------------------
// Flash attention: 64-q x 64-kv tiles, 4 waves x 16 q, 24.8 KB LDS ->
// 4+ blocks/CU resident (grid 1024 = 4/CU), 4 waves/SIMD for MFMA/VALU overlap.
// S^T trick + fixed stabilizer + XOR-swizzled LDS, base-2 softmax.
// ---------------------------------------------------------------------------
__global__ __launch_bounds__(256, 4) void attn_flash(
    const u16* __restrict__ qg, const u16* __restrict__ kg,
    const u16* __restrict__ vg, const float* __restrict__ mask,
    u16* __restrict__ ctx) {
  __shared__ u16 Ks[64 * 64];     // [kv][dh]  8 KB
  __shared__ u16 Vs[64 * 64];     // [dh][kv]  8 KB
  __shared__ u16 Pts[64 * 64];    // [q][kv]   8 KB (wave-private rows)
  __shared__ float mneg[64];

  const int tid = threadIdx.x;
  const int w = tid >> 6, lane = tid & 63;
  const int quad = lane >> 4, lq = lane & 15;
  const int q0 = blockIdx.x * 64;
  const int h = blockIdx.y, b = blockIdx.z;
  const long hoff = (long)(b * HH + h) * SS * DHH;

  // Q fragments (B-operand of S^T mfma); wave w owns q rows q0+w*16..+15
  v8s aq[2];
#pragma unroll
  for (int ks_ = 0; ks_ < 2; ks_++)
    aq[ks_] = *(const v8s*)(qg + hoff +
        (long)(q0 + w * 16 + lq) * DHH + ks_ * 32 + quad * 8);

  f32x4 o[4];
  float l_i = 0.f;
#pragma unroll
  for (int n_ = 0; n_ < 4; n_++)
#pragma unroll
    for (int r = 0; r < 4; r++) o[n_][r] = 0.f;

  const int qrow = w * 16 + lq;

  for (int kv0 = 0; kv0 < SS; kv0 += 64) {
    __syncthreads();
#pragma unroll
    for (int t = 0; t < 2; t++) {
      int c = tid + t * 256;           // 0..511
      int rk = c >> 3, ck = c & 7;     // 64 rows x 8 chunks
      *(v8s*)&Ks[rk * 64 + swz(rk, ck) * 8] =
          *(const v8s*)(kg + hoff + (long)(kv0 + rk) * DHH + ck * 8);
      *(v8s*)&Vs[rk * 64 + swz(rk, ck) * 8] =
          *(const v8s*)(vg + hoff + (long)rk * SS + kv0 + ck * 8);
    }
    if (tid < 16) {
      float4 mm = *(const float4*)(mask + (long)b * SS + kv0 + tid * 4);
      mneg[tid * 4 + 0] = (mm.x * -1e9f - 4.0f) * MSCALE;
      mneg[tid * 4 + 1] = (mm.y * -1e9f - 4.0f) * MSCALE;
      mneg[tid * 4 + 2] = (mm.z * -1e9f - 4.0f) * MSCALE;
      mneg[tid * 4 + 3] = (mm.w * -1e9f - 4.0f) * MSCALE;
    }
    __syncthreads();

    // S^T = K*Q^T: lane holds q = lq, kv = kv_*16 + quad*4 + r
    f32x4 sc[4];
#pragma unroll
    for (int kv_ = 0; kv_ < 4; kv_++)
#pragma unroll
      for (int r = 0; r < 4; r++) sc[kv_][r] = 0.f;
#pragma unroll
    for (int ks_ = 0; ks_ < 2; ks_++)
#pragma unroll
      for (int kv_ = 0; kv_ < 4; kv_++) {
        int rk = kv_ * 16 + lq;
        v8s ak = *(const v8s*)&Ks[rk * 64 + swz(rk, ks_ * 4 + quad) * 8];
        sc[kv_] = __builtin_amdgcn_mfma_f32_16x16x32_bf16(ak, aq[ks_], sc[kv_], 0, 0, 0);
      }

    float lsum = 0.f;
#pragma unroll
    for (int kv_ = 0; kv_ < 4; kv_++) {
      f32x4 mv = *(const f32x4*)&mneg[kv_ * 16 + quad * 4];
      float p0 = EXP_RAW(sc[kv_][0] + mv[0]);
      float p1 = EXP_RAW(sc[kv_][1] + mv[1]);
      float p2 = EXP_RAW(sc[kv_][2] + mv[2]);
      float p3 = EXP_RAW(sc[kv_][3] + mv[3]);
      lsum += (p0 + p1) + (p2 + p3);
      uint2 pk;
      pk.x = pk2(p0, p1);
      pk.y = pk2(p2, p3);
      int c8 = kv_ * 2 + (quad >> 1);
      *(uint2*)&Pts[qrow * 64 + swz(qrow, c8) * 8 + (quad & 1) * 4] = pk;
    }
    l_i += lsum;

    // O += P*V (A-frag from Pts, B-frag from Vs)
#pragma unroll
    for (int ks2 = 0; ks2 < 2; ks2++) {
      v8s bv[4];
#pragma unroll
      for (int n_ = 0; n_ < 4; n_++) {
        int rv = n_ * 16 + lq;
        bv[n_] = *(const v8s*)&Vs[rv * 64 + swz(rv, ks2 * 4 + quad) * 8];
      }
      v8s ap = *(const v8s*)&Pts[qrow * 64 + swz(qrow, ks2 * 4 + quad) * 8];
#pragma unroll
      for (int n_ = 0; n_ < 4; n_++)
        o[n_] = __builtin_amdgcn_mfma_f32_16x16x32_bf16(ap, bv[n_], o[n_], 0, 0, 0);
    }
  }

  // epilogue: normalize (l reduced across quads), store ctx [B,S,D] bf16
  float l = l_i;
  l += __shfl_xor(l, 16);
  l += __shfl_xor(l, 32);
  float inv = 1.0f / l;
  float ir[4];
  ir[0] = __shfl(inv, quad * 4 + 0);
  ir[1] = __shfl(inv, quad * 4 + 1);
  ir[2] = __shfl(inv, quad * 4 + 2);
  ir[3] = __shfl(inv, quad * 4 + 3);
#pragma unroll
  for (int r = 0; r < 4; r++) {
    int s = q0 + w * 16 + quad * 4 + r;
    long base = (long)(b * SS + s) * DD + h * DHH;
#pragma unroll
    for (int n_ = 0; n_ < 4; n_++)
      ctx[base + n_ * 16 + lq] = f2bf(o[n_][r] * ir[r]);
  }
}

// ---------------------------------------------------------------------------
extern "C" void kernel_launch(void* const* d_in, const int* in_sizes, int n_in,
                              void* d_out, int out_size, void* d_ws, size_t ws_size,
                              hipStream_t stream) {
  const float* query = (const float*)d_in[0];
  const float* key   = (const float*)d_in[1];
  const float* value = (const float*)d_in[2];
  const float* mask  = (const float*)d_in[3];
  const float* Wq = (const float*)d_in[4];
  const float* bq = (const float*)d_in[5];
  const float* Wk = (const float*)d_in[6];
  const float* bk = (const float*)d_in[7];
  const float* Wv = (const float*)d_in[8];
  const float* bv = (const float*)d_in[9];
  const float* Wo = (const float*)d_in[10];
  const float* bo = (const float*)d_in[11];

  u16* ws = (u16*)d_ws;
  const long A4 = (long)MM * DD;
  const long W1 = (long)DD * DD;
  u16* qb  = ws;
  u16* kb  = ws + A4;
  u16* vb  = ws + 2 * A4;
  u16* Wqt = ws + 3 * A4;
  u16* Wkt = Wqt + W1;
  u16* Wvt = Wkt + W1;
  u16* Wot = Wvt + W1;
  u16* q_ws   = ws + 3 * A4 + 4 * W1;
  u16* k_ws   = q_ws + A4;
  u16* v_ws   = k_ws + A4;
  u16* ctx_ws = v_ws + A4;

  prep_all<<<12288 + 1024, 256, 0, stream>>>(query, key, value, qb, kb, vb,
                                             Wq, Wk, Wv, Wo, Wqt, Wkt, Wvt, Wot);

  proj_fused<<<dim3(DD / 128, MM / 128, 3), 256, 0, stream>>>(
      qb, kb, vb, Wqt, Wkt, Wvt, bq, bk, bv, q_ws, k_ws, v_ws);

  attn_flash<<<dim3(SS / 64, HH, BB), 256, 0, stream>>>(q_ws, k_ws, v_ws, mask, ctx_ws);

  out_gemm<<<dim3(DD / 128, MM / 64), 256, 0, stream>>>(ctx_ws, Wot, bo, (float*)d_out);
}

// Round 10
// 229.996 us; speedup vs baseline: 1.0577x; 1.0577x over previous
//
#include <hip/hip_runtime.h>
#include <hip/hip_bf16.h>

// B=2, S=2048, D=1024, H=16, DH=64. fp32 in/out; bf16 MFMA inside.
#define BB 2
#define SS 2048
#define DD 1024
#define HH 16
#define DHH 64
#define MM (BB * SS)  // 4096

typedef unsigned short u16;
using v8s   = __attribute__((ext_vector_type(8))) short;   // 8 bf16 (4 VGPRs)
using f32x4 = __attribute__((ext_vector_type(4))) float;   // MFMA C/D frag

#define LOG2E 1.44269504088896340736f

#if __has_builtin(__builtin_amdgcn_exp2f)
#define EXP_RAW(x) __builtin_amdgcn_exp2f(x)
#define QSCALE (0.125f * LOG2E)
#define MSCALE LOG2E
#else
#define EXP_RAW(x) __expf(x)
#define QSCALE 0.125f
#define MSCALE 1.0f
#endif

__device__ __forceinline__ u16 f2bf(float f) {
  unsigned int u = __float_as_uint(f);
  u += 0x7fffu + ((u >> 16) & 1u);
  return (u16)(u >> 16);
}

__device__ __forceinline__ unsigned int pk2(float a, float b) {
  __hip_bfloat162 h = __float22bfloat162_rn(float2{a, b});
  return *(unsigned int*)&h;
}

__device__ __forceinline__ void async_cp16(const u16* g, u16* l) {
  __builtin_amdgcn_global_load_lds(
      (const __attribute__((address_space(1))) unsigned int*)g,
      (__attribute__((address_space(3))) unsigned int*)l, 16, 0, 0);
}

// XOR swizzle of 16B chunk index within 8-chunk (128 B) groups, keyed by row
__device__ __forceinline__ int swz(int r, int c8) {
  return (c8 & ~7) | ((c8 ^ r) & 7);
}

// ---------------------------------------------------------------------------
// Prep: fused fp32->bf16 activation convert (blocks 0..12287) and
// W->W^T bf16 transpose (blocks 12288..13311).
// ---------------------------------------------------------------------------
__global__ __launch_bounds__(256) void prep_all(
    const float* __restrict__ x0, const float* __restrict__ x1,
    const float* __restrict__ x2,
    u16* __restrict__ y0, u16* __restrict__ y1, u16* __restrict__ y2,
    const float* __restrict__ W0, const float* __restrict__ W1,
    const float* __restrict__ W2, const float* __restrict__ W3,
    u16* __restrict__ T0, u16* __restrict__ T1,
    u16* __restrict__ T2, u16* __restrict__ T3) {
  __shared__ u16 T[64][72];
  const int bid = blockIdx.x;
  const int tid = threadIdx.x;
  if (bid < 12288) {
    const int z = bid >> 12;
    const int bx = bid & 4095;
    const float* x = z == 0 ? x0 : (z == 1 ? x1 : x2);
    u16* y = z == 0 ? y0 : (z == 1 ? y1 : y2);
    int i = (bx * 256 + tid) * 4;
    float4 v = *(const float4*)(x + i);
    uint2 u;
    u.x = pk2(v.x, v.y);
    u.y = pk2(v.z, v.w);
    *(uint2*)(y + i) = u;
  } else {
    const int t = bid - 12288;
    const int z = t >> 8;
    const int tile = t & 255;
    const float* W = z == 0 ? W0 : (z == 1 ? W1 : (z == 2 ? W2 : W3));
    u16* Wt = z == 0 ? T0 : (z == 1 ? T1 : (z == 2 ? T2 : T3));
    const int n0 = (tile & 15) * 64, k0 = (tile >> 4) * 64;
#pragma unroll
    for (int i = 0; i < 4; i++) {
      int idx = tid + i * 256;
      int r = idx >> 4, c = (idx & 15) * 4;
      float4 x = *(const float4*)(W + (long)(k0 + r) * DD + n0 + c);
      T[c + 0][r] = f2bf(x.x);
      T[c + 1][r] = f2bf(x.y);
      T[c + 2][r] = f2bf(x.z);
      T[c + 3][r] = f2bf(x.w);
    }
    __syncthreads();
#pragma unroll
    for (int i = 0; i < 2; i++) {
      int idx = tid + i * 256;
      int n = idx >> 3, kc = (idx & 7) * 8;
      *(v8s*)(Wt + (long)(n0 + n) * DD + k0 + kc) = *(const v8s*)&T[n][kc];
    }
  }
}

// ---------------------------------------------------------------------------
// Fused Q/K/V projection GEMM: 128x128 tile, BK=64, global_load_lds.
// 1D grid 768, XCD-swizzled: xcd=bid%8 owns A-rows [4*xcd,4*xcd+4) for all z
// -> each XCD's L2 fetches its A rows + 3 weights once (72 MB total fabric
// traffic vs 384 MB unswizzled).
// ---------------------------------------------------------------------------
__global__ __launch_bounds__(256, 3) void proj_fused(
    const u16* __restrict__ qb, const u16* __restrict__ kb, const u16* __restrict__ vb,
    const u16* __restrict__ Wqt, const u16* __restrict__ Wkt, const u16* __restrict__ Wvt,
    const float* __restrict__ bq, const float* __restrict__ bk, const float* __restrict__ bv,
    u16* __restrict__ qo, u16* __restrict__ ko, u16* __restrict__ vo) {
  __shared__ union ShU {
    struct { u16 As[128 * 64]; u16 Bs[128 * 64]; } st;  // 32 KB
    u16 T[128 * 136];                                   // 34.8 KB
  } sh;
  const int bid = blockIdx.x;
  const int xcd = bid & 7, slot = bid >> 3;      // slot 0..95
  const int z = slot >> 5;                        // 0..2
  const int rem = slot & 31;
  const int row0 = (xcd * 4 + (rem >> 3)) * 128;  // rows partitioned by XCD
  const int col0 = (rem & 7) * 128;

  const u16* A  = z == 0 ? qb : (z == 1 ? kb : vb);
  const u16* Bt = z == 0 ? Wqt : (z == 1 ? Wkt : Wvt);
  const float* bias = z == 0 ? bq : (z == 1 ? bk : bv);
  u16* out = z == 0 ? qo : (z == 1 ? ko : vo);
  const float scale = z == 0 ? QSCALE : 1.0f;

  const int tid = threadIdx.x;
  const int w = tid >> 6, lane = tid & 63;
  const int quad = lane >> 4, lq = lane & 15;
  const int wm = w >> 1, wn = w & 1;

  f32x4 acc[4][4];
#pragma unroll
  for (int i = 0; i < 4; i++)
#pragma unroll
    for (int j = 0; j < 4; j++)
#pragma unroll
      for (int r = 0; r < 4; r++) acc[i][j][r] = 0.f;

  const int cr = tid >> 3, cc = (tid & 7) * 8;

  for (int k0 = 0; k0 < DD; k0 += 64) {
    __syncthreads();
#pragma unroll
    for (int it = 0; it < 4; it++) {
      async_cp16(A  + (long)(row0 + cr + it * 32) * DD + k0 + cc,
                 sh.st.As + (it * 256 + w * 64) * 8);
      async_cp16(Bt + (long)(col0 + cr + it * 32) * DD + k0 + cc,
                 sh.st.Bs + (it * 256 + w * 64) * 8);
    }
    __syncthreads();

#pragma unroll
    for (int kk = 0; kk < 2; kk++) {
      v8s a[4], b[4];
#pragma unroll
      for (int i = 0; i < 4; i++)
        a[i] = *(const v8s*)&sh.st.As[(wm * 64 + i * 16 + lq) * 64 + kk * 32 + quad * 8];
#pragma unroll
      for (int j = 0; j < 4; j++)
        b[j] = *(const v8s*)&sh.st.Bs[(wn * 64 + j * 16 + lq) * 64 + kk * 32 + quad * 8];
#pragma unroll
      for (int i = 0; i < 4; i++)
#pragma unroll
        for (int j = 0; j < 4; j++)
          acc[i][j] = __builtin_amdgcn_mfma_f32_16x16x32_bf16(a[i], b[j], acc[i][j], 0, 0, 0);
    }
  }

  __syncthreads();

  if (z != 2) {
#pragma unroll
    for (int j = 0; j < 4; j++) {
      int nl = wn * 64 + j * 16 + lq;
      float bi = bias[col0 + nl];
#pragma unroll
      for (int i = 0; i < 4; i++)
#pragma unroll
        for (int r = 0; r < 4; r++) {
          int ml = wm * 64 + i * 16 + quad * 4 + r;
          sh.T[ml * 136 + nl] = f2bf((acc[i][j][r] + bi) * scale);
        }
    }
    __syncthreads();
    const int bb = row0 >> 11;
#pragma unroll
    for (int t = 0; t < 8; t++) {
      int c = tid + t * 256;
      int m = c >> 4, jc = c & 15;
      int s = (row0 + m) & (SS - 1);
      int gn = col0 + jc * 8;
      int hh = gn >> 6, d = gn & (DHH - 1);
      long off = ((long)(bb * HH + hh) * SS + s) * DHH + d;
      *(v8s*)(out + off) = *(const v8s*)&sh.T[m * 136 + jc * 8];
    }
  } else {
#pragma unroll
    for (int j = 0; j < 4; j++) {
      int nl = wn * 64 + j * 16 + lq;
      float bi = bias[col0 + nl];
#pragma unroll
      for (int i = 0; i < 4; i++) {
        int ml = wm * 64 + i * 16 + quad * 4;
        uint2 pk;
        pk.x = pk2(acc[i][j][0] + bi, acc[i][j][1] + bi);
        pk.y = pk2(acc[i][j][2] + bi, acc[i][j][3] + bi);
        *(uint2*)&sh.T[nl * 136 + ml] = pk;
      }
    }
    __syncthreads();
    const int bb = row0 >> 11;
#pragma unroll
    for (int t = 0; t < 8; t++) {
      int c = tid + t * 256;
      int n = c >> 4, jc = c & 15;
      int gn = col0 + n;
      int hh = gn >> 6, d = gn & (DHH - 1);
      int s = (row0 + jc * 8) & (SS - 1);
      long off = ((long)(bb * HH + hh) * DHH + d) * SS + s;
      *(v8s*)(out + off) = *(const v8s*)&sh.T[n * 136 + jc * 8];
    }
  }
}

// ---------------------------------------------------------------------------
// Out GEMM: fp32 out = ctx(bf16)[M,K] @ Wot + bo. 64x128 tile, BK=64.
// 1D grid 512, XCD-swizzled: xcd owns 8 row-tiles -> Wo fetched once per XCD.
// ---------------------------------------------------------------------------
__global__ __launch_bounds__(256, 3) void out_gemm(const u16* __restrict__ A,
                                                   const u16* __restrict__ Bt,
                                                   const float* __restrict__ bias,
                                                   float* __restrict__ outp) {
  __shared__ u16 As[64 * 64];
  __shared__ u16 Bs[128 * 64];
  const int bid = blockIdx.x;
  const int xcd = bid & 7, slot = bid >> 3;      // slot 0..63
  const int row0 = (xcd * 8 + (slot >> 3)) * 64;
  const int col0 = (slot & 7) * 128;

  const int tid = threadIdx.x;
  const int w = tid >> 6, lane = tid & 63;
  const int quad = lane >> 4, lq = lane & 15;
  const int wm = w >> 1, wn = w & 1;

  f32x4 acc[2][4];
#pragma unroll
  for (int i = 0; i < 2; i++)
#pragma unroll
    for (int j = 0; j < 4; j++)
#pragma unroll
      for (int r = 0; r < 4; r++) acc[i][j][r] = 0.f;

  const int cr = tid >> 3, cc = (tid & 7) * 8;

  for (int k0 = 0; k0 < DD; k0 += 64) {
    __syncthreads();
#pragma unroll
    for (int it = 0; it < 2; it++)
      async_cp16(A + (long)(row0 + cr + it * 32) * DD + k0 + cc,
                 As + (it * 256 + w * 64) * 8);
#pragma unroll
    for (int it = 0; it < 4; it++)
      async_cp16(Bt + (long)(col0 + cr + it * 32) * DD + k0 + cc,
                 Bs + (it * 256 + w * 64) * 8);
    __syncthreads();

#pragma unroll
    for (int kk = 0; kk < 2; kk++) {
      v8s a[2], b[4];
#pragma unroll
      for (int i = 0; i < 2; i++)
        a[i] = *(const v8s*)&As[(wm * 32 + i * 16 + lq) * 64 + kk * 32 + quad * 8];
#pragma unroll
      for (int j = 0; j < 4; j++)
        b[j] = *(const v8s*)&Bs[(wn * 64 + j * 16 + lq) * 64 + kk * 32 + quad * 8];
#pragma unroll
      for (int i = 0; i < 2; i++)
#pragma unroll
        for (int j = 0; j < 4; j++)
          acc[i][j] = __builtin_amdgcn_mfma_f32_16x16x32_bf16(a[i], b[j], acc[i][j], 0, 0, 0);
    }
  }

#pragma unroll
  for (int i = 0; i < 2; i++)
#pragma unroll
    for (int j = 0; j < 4; j++) {
      int n = col0 + wn * 64 + j * 16 + lq;
      float bi = bias[n];
#pragma unroll
      for (int r = 0; r < 4; r++) {
        int m = row0 + wm * 32 + i * 16 + quad * 4 + r;
        outp[(long)m * DD + n] = acc[i][j][r] + bi;
      }
    }
}

// ---------------------------------------------------------------------------
// Flash attention (round-8 verified body): 128q x 128kv, 4 waves x 32 q,
// S^T trick + fixed stabilizer + XOR-swizzled LDS, base-2 softmax.
// 1D grid 512, XCD-swizzled: xcd owns 4 (b,h) heads -> K/V fetched once/XCD.
// ---------------------------------------------------------------------------
__global__ __launch_bounds__(256, 2) void attn_flash(
    const u16* __restrict__ qg, const u16* __restrict__ kg,
    const u16* __restrict__ vg, const float* __restrict__ mask,
    u16* __restrict__ ctx) {
  __shared__ u16 Ks[128 * 64];     // [kv][dh]   16 KB
  __shared__ u16 Vs[64 * 128];     // [dh][kv]   16 KB
  __shared__ u16 Pts[128 * 128];   // [q][kv]    32 KB
  __shared__ float mneg[128];

  const int bid = blockIdx.x;
  const int xcd = bid & 7, slot = bid >> 3;      // slot 0..63
  const int bh = xcd * 4 + (slot >> 4);          // 4 heads per XCD
  const int q0 = (slot & 15) * 128;
  const int b = bh >> 4, h = bh & 15;

  const int tid = threadIdx.x;
  const int w = tid >> 6, lane = tid & 63;
  const int quad = lane >> 4, lq = lane & 15;
  const long hoff = (long)(b * HH + h) * SS * DHH;

  v8s aq[2][2];
#pragma unroll
  for (int qs_ = 0; qs_ < 2; qs_++)
#pragma unroll
    for (int ks_ = 0; ks_ < 2; ks_++)
      aq[qs_][ks_] = *(const v8s*)(qg + hoff +
          (long)(q0 + w * 32 + qs_ * 16 + lq) * DHH + ks_ * 32 + quad * 8);

  f32x4 o[2][4];
  float l_i[2] = {0.f, 0.f};
#pragma unroll
  for (int a = 0; a < 2; a++)
#pragma unroll
    for (int n_ = 0; n_ < 4; n_++)
#pragma unroll
      for (int r = 0; r < 4; r++) o[a][n_][r] = 0.f;

  for (int kv0 = 0; kv0 < SS; kv0 += 128) {
    __syncthreads();
#pragma unroll
    for (int t = 0; t < 4; t++) {
      int c = tid + t * 256;
      int rk = c >> 3, ck = c & 7;     // Ks: 128 rows x 8 chunks
      *(v8s*)&Ks[rk * 64 + swz(rk, ck) * 8] =
          *(const v8s*)(kg + hoff + (long)(kv0 + rk) * DHH + ck * 8);
      int rv = c >> 4, cv = c & 15;    // Vs: 64 rows x 16 chunks
      *(v8s*)&Vs[rv * 128 + swz(rv, cv) * 8] =
          *(const v8s*)(vg + hoff + (long)rv * SS + kv0 + cv * 8);
    }
    if (tid < 32) {
      float4 mm = *(const float4*)(mask + (long)b * SS + kv0 + tid * 4);
      mneg[tid * 4 + 0] = (mm.x * -1e9f - 4.0f) * MSCALE;
      mneg[tid * 4 + 1] = (mm.y * -1e9f - 4.0f) * MSCALE;
      mneg[tid * 4 + 2] = (mm.z * -1e9f - 4.0f) * MSCALE;
      mneg[tid * 4 + 3] = (mm.w * -1e9f - 4.0f) * MSCALE;
    }
    __syncthreads();

    // S^T = K*Q^T: lane holds q = lq, kv = kv_*16 + quad*4 + r
    f32x4 sc[2][8];
#pragma unroll
    for (int qs_ = 0; qs_ < 2; qs_++)
#pragma unroll
      for (int kv_ = 0; kv_ < 8; kv_++)
#pragma unroll
        for (int r = 0; r < 4; r++) sc[qs_][kv_][r] = 0.f;
#pragma unroll
    for (int ks_ = 0; ks_ < 2; ks_++)
#pragma unroll
      for (int kv_ = 0; kv_ < 8; kv_++) {
        int rk = kv_ * 16 + lq;
        v8s ak = *(const v8s*)&Ks[rk * 64 + swz(rk, ks_ * 4 + quad) * 8];
        sc[0][kv_] = __builtin_amdgcn_mfma_f32_16x16x32_bf16(ak, aq[0][ks_], sc[0][kv_], 0, 0, 0);
        sc[1][kv_] = __builtin_amdgcn_mfma_f32_16x16x32_bf16(ak, aq[1][ks_], sc[1][kv_], 0, 0, 0);
      }

#pragma unroll
    for (int qs_ = 0; qs_ < 2; qs_++) {
      float lsum = 0.f;
      const int qrow = w * 32 + qs_ * 16 + lq;
#pragma unroll
      for (int kv_ = 0; kv_ < 8; kv_++) {
        f32x4 mv = *(const f32x4*)&mneg[kv_ * 16 + quad * 4];
        float p0 = EXP_RAW(sc[qs_][kv_][0] + mv[0]);
        float p1 = EXP_RAW(sc[qs_][kv_][1] + mv[1]);
        float p2 = EXP_RAW(sc[qs_][kv_][2] + mv[2]);
        float p3 = EXP_RAW(sc[qs_][kv_][3] + mv[3]);
        lsum += (p0 + p1) + (p2 + p3);
        uint2 pk;
        pk.x = pk2(p0, p1);
        pk.y = pk2(p2, p3);
        int c8 = kv_ * 2 + (quad >> 1);
        *(uint2*)&Pts[qrow * 128 + swz(qrow, c8) * 8 + (quad & 1) * 4] = pk;
      }
      l_i[qs_] += lsum;
    }

    // O += P*V
#pragma unroll
    for (int ks2 = 0; ks2 < 4; ks2++) {
      v8s bv[4];
#pragma unroll
      for (int n_ = 0; n_ < 4; n_++) {
        int rv = n_ * 16 + lq;
        bv[n_] = *(const v8s*)&Vs[rv * 128 + swz(rv, ks2 * 4 + quad) * 8];
      }
#pragma unroll
      for (int qs_ = 0; qs_ < 2; qs_++) {
        int qrow = w * 32 + qs_ * 16 + lq;
        v8s ap = *(const v8s*)&Pts[qrow * 128 + swz(qrow, ks2 * 4 + quad) * 8];
#pragma unroll
        for (int n_ = 0; n_ < 4; n_++)
          o[qs_][n_] = __builtin_amdgcn_mfma_f32_16x16x32_bf16(ap, bv[n_], o[qs_][n_], 0, 0, 0);
      }
    }
  }

  // epilogue: normalize (l reduced across quads), store ctx [B,S,D] bf16
#pragma unroll
  for (int qs_ = 0; qs_ < 2; qs_++) {
    float l = l_i[qs_];
    l += __shfl_xor(l, 16);
    l += __shfl_xor(l, 32);
    float inv = 1.0f / l;
    float ir[4];
    ir[0] = __shfl(inv, quad * 4 + 0);
    ir[1] = __shfl(inv, quad * 4 + 1);
    ir[2] = __shfl(inv, quad * 4 + 2);
    ir[3] = __shfl(inv, quad * 4 + 3);
#pragma unroll
    for (int r = 0; r < 4; r++) {
      int s = q0 + w * 32 + qs_ * 16 + quad * 4 + r;
      long base = (long)(b * SS + s) * DD + h * DHH;
#pragma unroll
      for (int n_ = 0; n_ < 4; n_++)
        ctx[base + n_ * 16 + lq] = f2bf(o[qs_][n_][r] * ir[r]);
    }
  }
}

// ---------------------------------------------------------------------------
extern "C" void kernel_launch(void* const* d_in, const int* in_sizes, int n_in,
                              void* d_out, int out_size, void* d_ws, size_t ws_size,
                              hipStream_t stream) {
  const float* query = (const float*)d_in[0];
  const float* key   = (const float*)d_in[1];
  const float* value = (const float*)d_in[2];
  const float* mask  = (const float*)d_in[3];
  const float* Wq = (const float*)d_in[4];
  const float* bq = (const float*)d_in[5];
  const float* Wk = (const float*)d_in[6];
  const float* bk = (const float*)d_in[7];
  const float* Wv = (const float*)d_in[8];
  const float* bv = (const float*)d_in[9];
  const float* Wo = (const float*)d_in[10];
  const float* bo = (const float*)d_in[11];

  u16* ws = (u16*)d_ws;
  const long A4 = (long)MM * DD;
  const long W1 = (long)DD * DD;
  u16* qb  = ws;
  u16* kb  = ws + A4;
  u16* vb  = ws + 2 * A4;
  u16* Wqt = ws + 3 * A4;
  u16* Wkt = Wqt + W1;
  u16* Wvt = Wkt + W1;
  u16* Wot = Wvt + W1;
  u16* q_ws   = ws + 3 * A4 + 4 * W1;
  u16* k_ws   = q_ws + A4;
  u16* v_ws   = k_ws + A4;
  u16* ctx_ws = v_ws + A4;

  prep_all<<<12288 + 1024, 256, 0, stream>>>(query, key, value, qb, kb, vb,
                                             Wq, Wk, Wv, Wo, Wqt, Wkt, Wvt, Wot);

  proj_fused<<<768, 256, 0, stream>>>(qb, kb, vb, Wqt, Wkt, Wvt,
                                      bq, bk, bv, q_ws, k_ws, v_ws);

  attn_flash<<<512, 256, 0, stream>>>(q_ws, k_ws, v_ws, mask, ctx_ws);

  out_gemm<<<512, 256, 0, stream>>>(ctx_ws, Wot, bo, (float*)d_out);
}